// Round 6
// baseline (316.608 us; speedup 1.0000x reference)
//
#include <hip/hip_runtime.h>
#include <hip/hip_bf16.h>

// Problem constants (match reference)
#define NN 50000
#define NE 500000
// D_NODE=64, D_EDGE=8, D_MSG=64, H_MSG=128, H_UPD=64, H_TEN=32, D_OUT=32

typedef _Float16 half8 __attribute__((ext_vector_type(8)));
typedef float f32x4 __attribute__((ext_vector_type(4)));

#define MFMA16(a, b, c) __builtin_amdgcn_mfma_f32_16x16x32_f16(a, b, c, 0, 0, 0)

__device__ __forceinline__ float h2f(unsigned short b) {
    return (float)__builtin_bit_cast(_Float16, b);
}

// ===========================================================================
// CSR-build: hist -> 3-phase hierarchical scan -> place (inverse perm pos[])
// Directed edge d in [0,2E): d<NE is fwd (tgt=ei[NE+d]); d>=NE bwd (tgt=ei[d-NE])
// ===========================================================================
__global__ void hist_kernel(const int* __restrict__ ei, int* __restrict__ deg) {
    int e = blockIdx.x * blockDim.x + threadIdx.x;
    if (e < NE) {
        atomicAdd(&deg[ei[NE + e]], 1);   // fwd message targets t
        atomicAdd(&deg[ei[e]], 1);        // bwd message targets s
    }
}

#define SCAN_NBLK ((NN + 255) / 256)   // 196

__global__ __launch_bounds__(256) void scan1_kernel(
    const int* __restrict__ deg, int* __restrict__ off, int* __restrict__ part) {
    __shared__ int sh[256];
    const int t = threadIdx.x;
    const int i = blockIdx.x * 256 + t;
    const int v = (i < NN) ? deg[i] : 0;
    sh[t] = v;
    __syncthreads();
    for (int d = 1; d < 256; d <<= 1) {
        int u = (t >= d) ? sh[t - d] : 0;
        __syncthreads();
        sh[t] += u;
        __syncthreads();
    }
    if (i < NN) off[i] = sh[t] - v;            // exclusive local
    if (t == 255) part[blockIdx.x] = sh[255];  // block total
}

__global__ __launch_bounds__(256) void scan2_kernel(int* __restrict__ part) {
    __shared__ int sh[256];
    const int t = threadIdx.x;
    const int v = (t < SCAN_NBLK) ? part[t] : 0;
    sh[t] = v;
    __syncthreads();
    for (int d = 1; d < 256; d <<= 1) {
        int u = (t >= d) ? sh[t - d] : 0;
        __syncthreads();
        sh[t] += u;
        __syncthreads();
    }
    if (t < SCAN_NBLK) part[t] = sh[t] - v;    // exclusive
}

__global__ __launch_bounds__(256) void scan3_kernel(
    int* __restrict__ off, int* __restrict__ cursor, const int* __restrict__ part) {
    const int t = threadIdx.x;
    const int i = blockIdx.x * 256 + t;
    if (i < NN) {
        const int o = off[i] + part[blockIdx.x];
        off[i] = o;
        cursor[i] = o;
    }
    if (i == 0) off[NN] = 2 * NE;
}

__global__ void place_kernel(const int* __restrict__ ei,
                             int* __restrict__ cursor, int* __restrict__ pos) {
    int e = blockIdx.x * blockDim.x + threadIdx.x;
    if (e < NE) {
        int t = ei[NE + e]; pos[e]      = atomicAdd(&cursor[t], 1);  // fwd slot
        int s = ei[e];      pos[NE + e] = atomicAdd(&cursor[s], 1);  // bwd slot
    }
}

// ===========================================================================
// Edge kernel (MFMA): 8 waves/block (512 thr), batches of 16 edge-pairs.
// Layouts (HW-verified round 3):
//   A-frag: lane l holds A[row=l&15][k=(l>>4)*8+i]
//   B-frag: lane l holds B[k=(l>>4)*8+i][col=l&15]
//   C/D   : lane l holds D[row=(l>>4)*4+r][col=l&15]
// Messages are written TARGET-SORTED (msg[pos[d]]) as FULL 128B LINES
// (8 lanes x dwordx4 per row, staged via LDS) to avoid write-allocate RFO.
// ===========================================================================
#define SW 136   // scratch row stride in halfs (272 B, 16B-aligned rows)
#define EW 8     // waves per block

__global__ __launch_bounds__(512) void edge_mfma_kernel(
    const float* __restrict__ x, const int* __restrict__ ei,
    const float* __restrict__ ea, const int* __restrict__ pos,
    const float* __restrict__ Wm1, const float* __restrict__ bm1,
    const float* __restrict__ Wm2, const float* __restrict__ bm2,
    const float* __restrict__ Wt1, const float* __restrict__ bt1,
    const float* __restrict__ Wt2, const float* __restrict__ bt2,
    _Float16* __restrict__ msg, float* __restrict__ e_out)
{
    __shared__ __align__(16) _Float16 wm1_sw[3 * 8 * 64 * 8];   // 24 KB
    __shared__ __align__(16) _Float16 wm2_sw[4 * 4 * 64 * 8];   // 16 KB
    __shared__ __align__(16) _Float16 wt1_sw[2 * 2 * 64 * 8];   //  4 KB
    __shared__ __align__(16) _Float16 hscr[EW * 16 * SW];       // 34 KB

    const int tid = threadIdx.x;
    for (int idx = tid; idx < 12288; idx += 512) {   // Wm1 [72,128] pad K->96
        int i = idx & 7, l = (idx >> 3) & 63, nt = (idx >> 9) & 7, kt = idx >> 12;
        int k = kt * 32 + ((l >> 4) << 3) + i, n = nt * 16 + (l & 15);
        wm1_sw[idx] = (k < 72) ? (_Float16)Wm1[k * 128 + n] : (_Float16)0.f;
    }
    for (int idx = tid; idx < 8192; idx += 512) {    // Wm2 [128,64]
        int i = idx & 7, l = (idx >> 3) & 63, nt = (idx >> 9) & 3, kt = idx >> 11;
        int k = kt * 32 + ((l >> 4) << 3) + i, n = nt * 16 + (l & 15);
        wm2_sw[idx] = (_Float16)Wm2[k * 64 + n];
    }
    for (int idx = tid; idx < 2048; idx += 512) {    // Wt1^T as A-frags [32,64]
        int i = idx & 7, l = (idx >> 3) & 63, kt = (idx >> 9) & 1, jt = idx >> 10;
        int k = kt * 32 + ((l >> 4) << 3) + i, j = jt * 16 + (l & 15);
        wt1_sw[idx] = (_Float16)Wt1[k * 32 + j];
    }
    __syncthreads();

    const int lane = tid & 63;
    const int g = lane >> 4;
    const int c = lane & 15;
    const int wid = tid >> 6;
    _Float16* hs = &hscr[wid * 16 * SW];

    float bm1v[8], bm2v[4], bt1v[8], wt2v[8];
#pragma unroll
    for (int nt = 0; nt < 8; ++nt) bm1v[nt] = bm1[nt * 16 + c];
#pragma unroll
    for (int nt = 0; nt < 4; ++nt) bm2v[nt] = bm2[nt * 16 + c];
#pragma unroll
    for (int jt = 0; jt < 2; ++jt)
#pragma unroll
        for (int r = 0; r < 4; ++r) {
            int j = jt * 16 + g * 4 + r;
            bt1v[jt * 4 + r] = bt1[j];
            wt2v[jt * 4 + r] = Wt2[j];
        }
    const float bt2v = bt2[0];

    const float4* xp = (const float4*)x;
    const float4* eap = (const float4*)ea;

    // flush-pass lane mapping: 8 lanes per msg row, dwordx4 chunks
    const int frow = lane >> 3;    // 0..7 (row within pass)
    const int fchk = lane & 7;     // 16B chunk within the 128B row

    const int gwave = blockIdx.x * EW + wid;
    const int nwave = gridDim.x * EW;
    const int NB = NE / 16;   // 31250 exact

    for (int bt = gwave; bt < NB; bt += nwave) {
        const int eb = bt * 16;
        const int e = eb + c;
        const int sv = ei[e];
        const int tv = ei[NE + e];

        // ---- build A1 fragments (diff in k<64, ea in k=64..71, pad 0) ----
        half8 a0, a1, a2;
        {
            float4 t0 = xp[(size_t)tv * 16 + g * 2];
            float4 t1 = xp[(size_t)tv * 16 + g * 2 + 1];
            float4 s0 = xp[(size_t)sv * 16 + g * 2];
            float4 s1 = xp[(size_t)sv * 16 + g * 2 + 1];
            a0[0] = (_Float16)(t0.x - s0.x); a0[1] = (_Float16)(t0.y - s0.y);
            a0[2] = (_Float16)(t0.z - s0.z); a0[3] = (_Float16)(t0.w - s0.w);
            a0[4] = (_Float16)(t1.x - s1.x); a0[5] = (_Float16)(t1.y - s1.y);
            a0[6] = (_Float16)(t1.z - s1.z); a0[7] = (_Float16)(t1.w - s1.w);
            float4 t2 = xp[(size_t)tv * 16 + 8 + g * 2];
            float4 t3 = xp[(size_t)tv * 16 + 8 + g * 2 + 1];
            float4 s2 = xp[(size_t)sv * 16 + 8 + g * 2];
            float4 s3 = xp[(size_t)sv * 16 + 8 + g * 2 + 1];
            a1[0] = (_Float16)(t2.x - s2.x); a1[1] = (_Float16)(t2.y - s2.y);
            a1[2] = (_Float16)(t2.z - s2.z); a1[3] = (_Float16)(t2.w - s2.w);
            a1[4] = (_Float16)(t3.x - s3.x); a1[5] = (_Float16)(t3.y - s3.y);
            a1[6] = (_Float16)(t3.z - s3.z); a1[7] = (_Float16)(t3.w - s3.w);
        }
        a2 = (half8)(_Float16)0.f;
        if (g == 0) {
            float4 e0 = eap[(size_t)e * 2];
            float4 e1 = eap[(size_t)e * 2 + 1];
            a2[0] = (_Float16)e0.x; a2[1] = (_Float16)e0.y;
            a2[2] = (_Float16)e0.z; a2[3] = (_Float16)e0.w;
            a2[4] = (_Float16)e1.x; a2[5] = (_Float16)e1.y;
            a2[6] = (_Float16)e1.z; a2[7] = (_Float16)e1.w;
        }

        // ---- layer 1: Z[16,128] = A1[16,96] @ Wm1 ----
        f32x4 z[8];
#pragma unroll
        for (int nt = 0; nt < 8; ++nt) z[nt] = (f32x4)0.f;
#pragma unroll
        for (int nt = 0; nt < 8; ++nt) {
            z[nt] = MFMA16(a0, *(const half8*)&wm1_sw[((0 * 8 + nt) * 64 + lane) * 8], z[nt]);
            z[nt] = MFMA16(a1, *(const half8*)&wm1_sw[((1 * 8 + nt) * 64 + lane) * 8], z[nt]);
            z[nt] = MFMA16(a2, *(const half8*)&wm1_sw[((2 * 8 + nt) * 64 + lane) * 8], z[nt]);
        }

        // ---- hf = relu(z+b) -> scratch -> A-frags; layer2 fwd ----
#pragma unroll
        for (int nt = 0; nt < 8; ++nt)
#pragma unroll
            for (int r = 0; r < 4; ++r)
                hs[(g * 4 + r) * SW + nt * 16 + c] = (_Float16)fmaxf(z[nt][r] + bm1v[nt], 0.f);
        half8 hA[4];
#pragma unroll
        for (int kt = 0; kt < 4; ++kt)
            hA[kt] = *(const half8*)&hs[c * SW + kt * 32 + g * 8];
        f32x4 m_f[4];
#pragma unroll
        for (int nt = 0; nt < 4; ++nt) m_f[nt] = (f32x4)0.f;
#pragma unroll
        for (int kt = 0; kt < 4; ++kt)
#pragma unroll
            for (int nt = 0; nt < 4; ++nt)
                m_f[nt] = MFMA16(hA[kt], *(const half8*)&wm2_sw[((kt * 4 + nt) * 64 + lane) * 8], m_f[nt]);

        // ---- hb = relu(b-z) -> scratch -> A-frags; layer2 bwd ----
#pragma unroll
        for (int nt = 0; nt < 8; ++nt)
#pragma unroll
            for (int r = 0; r < 4; ++r)
                hs[(g * 4 + r) * SW + nt * 16 + c] = (_Float16)fmaxf(bm1v[nt] - z[nt][r], 0.f);
#pragma unroll
        for (int kt = 0; kt < 4; ++kt)
            hA[kt] = *(const half8*)&hs[c * SW + kt * 32 + g * 8];
        f32x4 m_b[4];
#pragma unroll
        for (int nt = 0; nt < 4; ++nt) m_b[nt] = (f32x4)0.f;
#pragma unroll
        for (int kt = 0; kt < 4; ++kt)
#pragma unroll
            for (int nt = 0; nt < 4; ++nt)
                m_b[nt] = MFMA16(hA[kt], *(const half8*)&wm2_sw[((kt * 4 + nt) * 64 + lane) * 8], m_b[nt]);

        // ---- bias+relu (keep in regs); msym -> scratch for tension ----
#pragma unroll
        for (int nt = 0; nt < 4; ++nt)
#pragma unroll
            for (int r = 0; r < 4; ++r) {
                const float mfv = fmaxf(m_f[nt][r] + bm2v[nt], 0.f);
                const float mbv = fmaxf(m_b[nt][r] + bm2v[nt], 0.f);
                m_f[nt][r] = mfv;
                m_b[nt][r] = mbv;
                hs[(g * 4 + r) * SW + nt * 16 + c] = (_Float16)(mfv + mbv);
            }

        // ---- tension: D'[j, e] = Wt1^T @ m_sym^T ----
        half8 mB[2];
#pragma unroll
        for (int kt = 0; kt < 2; ++kt)
            mB[kt] = *(const half8*)&hs[c * SW + kt * 32 + g * 8];
        f32x4 ct[2];
        ct[0] = (f32x4)0.f; ct[1] = (f32x4)0.f;
#pragma unroll
        for (int jt = 0; jt < 2; ++jt)
#pragma unroll
            for (int kt = 0; kt < 2; ++kt)
                ct[jt] = MFMA16(*(const half8*)&wt1_sw[((jt * 2 + kt) * 64 + lane) * 8], mB[kt], ct[jt]);
        float p = 0.f;
#pragma unroll
        for (int jt = 0; jt < 2; ++jt)
#pragma unroll
            for (int r = 0; r < 4; ++r)
                p += fmaxf(ct[jt][r] + bt1v[jt * 4 + r], 0.f) * wt2v[jt * 4 + r];
        p += __shfl_xor(p, 16);
        p += __shfl_xor(p, 32);
        if (lane < 16) e_out[eb + c] = p + bt2v;

        // ---- stage mf in LDS, flush as FULL 128B rows (8 lanes x 16B) ----
#pragma unroll
        for (int nt = 0; nt < 4; ++nt)
#pragma unroll
            for (int r = 0; r < 4; ++r)
                hs[(g * 4 + r) * SW + nt * 16 + c] = (_Float16)m_f[nt][r];
#pragma unroll
        for (int pA = 0; pA < 2; ++pA) {
            const int row = pA * 8 + frow;
            const int prow = pos[eb + row];
            const half8 v = *(const half8*)&hs[row * SW + fchk * 8];
            *(half8*)&msg[(size_t)prow * 64 + fchk * 8] = v;
        }

        // ---- stage mb in LDS, flush ----
#pragma unroll
        for (int nt = 0; nt < 4; ++nt)
#pragma unroll
            for (int r = 0; r < 4; ++r)
                hs[(g * 4 + r) * SW + nt * 16 + c] = (_Float16)m_b[nt][r];
#pragma unroll
        for (int pB = 0; pB < 2; ++pB) {
            const int row = pB * 8 + frow;
            const int prow = pos[NE + eb + row];
            const half8 v = *(const half8*)&hs[row * SW + fchk * 8];
            *(half8*)&msg[(size_t)prow * 64 + fchk * 8] = v;
        }
    }
}

// ===========================================================================
// Aggregation kernel: ONE WAVE PER NODE. msg is target-sorted, so each node
// reads a CONTIGUOUS block of rows [off[n], off[n+1]) -- pure streaming.
// Writes aggr (f16, packed u32) into the x_out region of d_out.
// ===========================================================================
__global__ __launch_bounds__(256) void aggr_kernel(
    const _Float16* __restrict__ msg, const int* __restrict__ off,
    unsigned int* __restrict__ aggr_u32)
{
    const int lane = threadIdx.x & 63;
    const int wid  = threadIdx.x >> 6;
    const int n    = blockIdx.x * 4 + wid;
    if (n >= NN) return;

    const int b = off[n], en = off[n + 1];
    const unsigned int* msg_u32 = (const unsigned int*)msg;
    const int half = lane >> 5;
    const int col  = lane & 31;

    float a0 = 0.f, a1 = 0.f, a2 = 0.f, a3 = 0.f;
    float a4 = 0.f, a5 = 0.f, a6 = 0.f, a7 = 0.f;
    int it = b + half;
    for (; it + 6 < en; it += 8) {
        const unsigned int d0 = msg_u32[(size_t)it * 32 + col];
        const unsigned int d1 = msg_u32[(size_t)(it + 2) * 32 + col];
        const unsigned int d2 = msg_u32[(size_t)(it + 4) * 32 + col];
        const unsigned int d3 = msg_u32[(size_t)(it + 6) * 32 + col];
        a0 += h2f((unsigned short)(d0 & 0xffffu)); a1 += h2f((unsigned short)(d0 >> 16));
        a2 += h2f((unsigned short)(d1 & 0xffffu)); a3 += h2f((unsigned short)(d1 >> 16));
        a4 += h2f((unsigned short)(d2 & 0xffffu)); a5 += h2f((unsigned short)(d2 >> 16));
        a6 += h2f((unsigned short)(d3 & 0xffffu)); a7 += h2f((unsigned short)(d3 >> 16));
    }
    for (; it < en; it += 2) {
        const unsigned int d = msg_u32[(size_t)it * 32 + col];
        a0 += h2f((unsigned short)(d & 0xffffu)); a1 += h2f((unsigned short)(d >> 16));
    }
    float lo = (a0 + a2) + (a4 + a6);
    float hi = (a1 + a3) + (a5 + a7);
    lo += __shfl_xor(lo, 32);
    hi += __shfl_xor(hi, 32);
    const float inv = 1.f / fmaxf((float)(en - b), 1.f);
    if (lane < 32) {
        unsigned short l16 = __builtin_bit_cast(unsigned short, (_Float16)(lo * inv));
        unsigned short h16 = __builtin_bit_cast(unsigned short, (_Float16)(hi * inv));
        aggr_u32[(size_t)n * 32 + lane] = (unsigned int)l16 | ((unsigned int)h16 << 16);
    }
}

// ===========================================================================
// Node MLP kernel: gather-free. [x | aggr][16,128] @ Wu1 -> relu -> @ Wu2.
// aggr aliases x_out bytes; each node's aggr bytes are read (into MFMA
// operands) by the same wave before the dependent x_out store -> safe.
// ===========================================================================
#define SWN 72

__global__ __launch_bounds__(256) void node_mlp_kernel(
    const float* __restrict__ x,
    const float* __restrict__ Wu1, const float* __restrict__ bu1,
    const float* __restrict__ Wu2, const float* __restrict__ bu2,
    const _Float16* aggr, float* x_out)
{
    __shared__ __align__(16) _Float16 wu1_sw[4 * 4 * 64 * 8];   // 16 KB
    __shared__ __align__(16) _Float16 wu2_sw[2 * 2 * 64 * 8];   //  4 KB
    __shared__ __align__(16) _Float16 nscr[4 * 16 * SWN];       //  9 KB

    const int tid = threadIdx.x;
    for (int idx = tid; idx < 8192; idx += 256) {
        int i = idx & 7, l = (idx >> 3) & 63, nt = (idx >> 9) & 3, kt = idx >> 11;
        int k = kt * 32 + ((l >> 4) << 3) + i, n = nt * 16 + (l & 15);
        wu1_sw[idx] = (_Float16)Wu1[k * 64 + n];
    }
    for (int idx = tid; idx < 2048; idx += 256) {
        int i = idx & 7, l = (idx >> 3) & 63, kt = (idx >> 9) & 1, jt = idx >> 10;
        int k = kt * 32 + ((l >> 4) << 3) + i, j = jt * 16 + (l & 15);
        wu2_sw[idx] = (_Float16)Wu2[k * 32 + j];
    }
    __syncthreads();

    const int lane = tid & 63;
    const int g = lane >> 4;
    const int c = lane & 15;
    const int wid = tid >> 6;
    _Float16* ns = &nscr[wid * 16 * SWN];

    float bu1v[4], bu2v[8];
#pragma unroll
    for (int nt = 0; nt < 4; ++nt) bu1v[nt] = bu1[nt * 16 + c];
#pragma unroll
    for (int jt = 0; jt < 2; ++jt)
#pragma unroll
        for (int r = 0; r < 4; ++r) bu2v[jt * 4 + r] = bu2[jt * 16 + g * 4 + r];

    const float4* xp = (const float4*)x;

    const int gwave = blockIdx.x * 4 + wid;
    const int nwave = gridDim.x * 4;
    const int NB = NN / 16;   // 3125 exact

    for (int bt = gwave; bt < NB; bt += nwave) {
        const int nbase = bt * 16;
        const int nn_ = nbase + c;

        half8 af[4];
        {
            float4 x0 = xp[(size_t)nn_ * 16 + g * 2];
            float4 x1 = xp[(size_t)nn_ * 16 + g * 2 + 1];
            af[0][0] = (_Float16)x0.x; af[0][1] = (_Float16)x0.y;
            af[0][2] = (_Float16)x0.z; af[0][3] = (_Float16)x0.w;
            af[0][4] = (_Float16)x1.x; af[0][5] = (_Float16)x1.y;
            af[0][6] = (_Float16)x1.z; af[0][7] = (_Float16)x1.w;
            float4 x2 = xp[(size_t)nn_ * 16 + 8 + g * 2];
            float4 x3 = xp[(size_t)nn_ * 16 + 8 + g * 2 + 1];
            af[1][0] = (_Float16)x2.x; af[1][1] = (_Float16)x2.y;
            af[1][2] = (_Float16)x2.z; af[1][3] = (_Float16)x2.w;
            af[1][4] = (_Float16)x3.x; af[1][5] = (_Float16)x3.y;
            af[1][6] = (_Float16)x3.z; af[1][7] = (_Float16)x3.w;
        }
        af[2] = *(const half8*)&aggr[(size_t)nn_ * 64 + g * 8];
        af[3] = *(const half8*)&aggr[(size_t)nn_ * 64 + 32 + g * 8];

        f32x4 hu[4];
#pragma unroll
        for (int nt = 0; nt < 4; ++nt) hu[nt] = (f32x4)0.f;
#pragma unroll
        for (int kt = 0; kt < 4; ++kt)
#pragma unroll
            for (int nt = 0; nt < 4; ++nt)
                hu[nt] = MFMA16(af[kt], *(const half8*)&wu1_sw[((kt * 4 + nt) * 64 + lane) * 8], hu[nt]);

#pragma unroll
        for (int nt = 0; nt < 4; ++nt)
#pragma unroll
            for (int r = 0; r < 4; ++r)
                ns[(g * 4 + r) * SWN + nt * 16 + c] = (_Float16)fmaxf(hu[nt][r] + bu1v[nt], 0.f);

        half8 hB[2];
#pragma unroll
        for (int kt = 0; kt < 2; ++kt)
            hB[kt] = *(const half8*)&ns[c * SWN + kt * 32 + g * 8];
        f32x4 co[2];
        co[0] = (f32x4)0.f; co[1] = (f32x4)0.f;
#pragma unroll
        for (int jt = 0; jt < 2; ++jt)
#pragma unroll
            for (int kt = 0; kt < 2; ++kt)
                co[jt] = MFMA16(*(const half8*)&wu2_sw[((jt * 2 + kt) * 64 + lane) * 8], hB[kt], co[jt]);

#pragma unroll
        for (int jt = 0; jt < 2; ++jt)
#pragma unroll
            for (int r = 0; r < 4; ++r)
                x_out[(size_t)nn_ * 32 + jt * 16 + g * 4 + r] = co[jt][r] + bu2v[jt * 4 + r];
    }
}

extern "C" void kernel_launch(void* const* d_in, const int* in_sizes, int n_in,
                              void* d_out, int out_size, void* d_ws, size_t ws_size,
                              hipStream_t stream) {
    const float* x   = (const float*)d_in[0];
    const int*   ei  = (const int*)d_in[1];
    const float* ea  = (const float*)d_in[2];
    const float* Wm1 = (const float*)d_in[3];
    const float* bm1 = (const float*)d_in[4];
    const float* Wm2 = (const float*)d_in[5];
    const float* bm2 = (const float*)d_in[6];
    const float* Wu1 = (const float*)d_in[7];
    const float* bu1 = (const float*)d_in[8];
    const float* Wu2 = (const float*)d_in[9];
    const float* bu2 = (const float*)d_in[10];
    const float* Wt1 = (const float*)d_in[11];
    const float* bt1 = (const float*)d_in[12];
    const float* Wt2 = (const float*)d_in[13];
    const float* bt2 = (const float*)d_in[14];

    float* x_out = (float*)d_out;
    float* e_out = x_out + (size_t)NN * 32;

    const size_t msg_bytes = (size_t)2 * NE * 64 * sizeof(_Float16); // 128 MB
    _Float16* msg = (_Float16*)d_ws;
    int* pos    = (int*)((char*)d_ws + msg_bytes);  // [2E] inverse permutation
    int* deg    = pos + (size_t)2 * NE;             // [NN]
    int* off    = deg + NN;                         // [NN+1]
    int* cursor = off + NN + 1;                     // [NN]
    int* part   = cursor + NN;                      // [SCAN_NBLK]

    hipMemsetAsync(deg, 0, (size_t)NN * sizeof(int), stream);
    hist_kernel<<<(NE + 1023) / 1024, 1024, 0, stream>>>(ei, deg);
    scan1_kernel<<<SCAN_NBLK, 256, 0, stream>>>(deg, off, part);
    scan2_kernel<<<1, 256, 0, stream>>>(part);
    scan3_kernel<<<SCAN_NBLK, 256, 0, stream>>>(off, cursor, part);
    place_kernel<<<(NE + 1023) / 1024, 1024, 0, stream>>>(ei, cursor, pos);

    edge_mfma_kernel<<<1024, 512, 0, stream>>>(x, ei, ea, pos, Wm1, bm1, Wm2, bm2,
                                               Wt1, bt1, Wt2, bt2, msg, e_out);

    // aggr (f16) aliases the x_out region of d_out (same byte extent)
    aggr_kernel<<<(NN + 3) / 4, 256, 0, stream>>>(msg, off, (unsigned int*)d_out);
    node_mlp_kernel<<<782, 256, 0, stream>>>(x, Wu1, bu1, Wu2, bu2,
                                             (const _Float16*)d_out, x_out);
}